// Round 3
// baseline (1790.602 us; speedup 1.0000x reference)
//
#include <hip/hip_runtime.h>

// LSTM B=128,T=1024,H=128,D=64,L=3.
// R3: compressed h exchange (1 KB/buffer, broadcast ds_read, conflict-free),
// dual MFMA chains (dep depth 2), register-prefetched xg, lgkm-only barrier.

#define BATCH 128
#define TT    1024
#define HH    128
#define DD    64
#define NB    4        // batches per recurrence WG
#define PD    4        // xg register prefetch depth (steps)

typedef __attribute__((ext_vector_type(4))) float f32x4;
typedef __attribute__((ext_vector_type(8))) short bf16x8;
typedef __attribute__((ext_vector_type(4))) short bf16x4;

__device__ inline unsigned short f2bf(float f) {           // RNE
  unsigned u = __builtin_bit_cast(unsigned, f);
  u += 0x7FFFu + ((u >> 16) & 1u);
  return (unsigned short)(u >> 16);
}
__device__ inline float bf2f(unsigned short s) {
  return __builtin_bit_cast(float, (unsigned)s << 16);
}
__device__ inline float fsig(float x) {
  return __builtin_amdgcn_rcpf(1.f + __builtin_amdgcn_exp2f(-1.442695041f * x));
}
__device__ inline float ftanh(float x) {
  return 2.f * __builtin_amdgcn_rcpf(1.f + __builtin_amdgcn_exp2f(-2.885390082f * x)) - 1.f;
}
__device__ inline bf16x8 pack8(f32x4 a, f32x4 b) {
  bf16x8 r;
  r[0]=(short)f2bf(a[0]); r[1]=(short)f2bf(a[1]); r[2]=(short)f2bf(a[2]); r[3]=(short)f2bf(a[3]);
  r[4]=(short)f2bf(b[0]); r[5]=(short)f2bf(b[1]); r[6]=(short)f2bf(b[2]); r[7]=(short)f2bf(b[3]);
  return r;
}
// LDS-only barrier: does NOT drain vmcnt -> global prefetch stays in flight.
__device__ inline void bar_lds() {
  asm volatile("s_waitcnt lgkmcnt(0)\n\ts_barrier" ::: "memory");
}

// ---------------- fp32 -> bf16 convert ----------------
__global__ void cvt_bf16(const float* __restrict__ x, unsigned short* __restrict__ xb, int n) {
  int i = (blockIdx.x * 256 + threadIdx.x) * 4;
  if (i < n) {
    f32x4 v = *(const f32x4*)(x + i);
    bf16x4 s;
    s[0]=(short)f2bf(v[0]); s[1]=(short)f2bf(v[1]); s[2]=(short)f2bf(v[2]); s[3]=(short)f2bf(v[3]);
    *(bf16x4*)(xb + i) = s;
  }
}

// ---------------- xg GEMM: [BT x K] @ [K x 512] + bias -> bf16 ----------------
// Output layout: xg[row][j][q] (row=b*T+t, j=hidden unit, q=gate) -> one 8B
// load per thread per recurrence step.
template<int K>
__global__ __launch_bounds__(256, 2) void xg_gemm(
    const unsigned short* __restrict__ A,     // [BT][K] bf16
    const float* __restrict__ Wih,            // [512][K] fp32
    const float* __restrict__ bih, const float* __restrict__ bhh,
    unsigned short* __restrict__ xg)          // [BT][128][4] bf16
{
  constexpr int KC = K / 32;
  constexpr int ASTR = K * 2 + 16;
  __shared__ char alds[64 * ASTR];
  int tid = threadIdx.x, wave = tid >> 6, lane = tid & 63, quad = lane >> 4, l15 = lane & 15;
  size_t M0 = (size_t)blockIdx.x * 64;

#pragma unroll
  for (int v = 0; v < (64 * K) / (256 * 8); ++v) {
    int e = (tid + v * 256) * 8;
    int row = e / K, col = e % K;
    bf16x8 d = *(const bf16x8*)(A + M0 * K + e);
    *(bf16x8*)(alds + row * ASTR + col * 2) = d;
  }
  __syncthreads();

  bf16x8 af[4][KC];
#pragma unroll
  for (int mt = 0; mt < 4; ++mt)
#pragma unroll
    for (int kc = 0; kc < KC; ++kc)
      af[mt][kc] = *(const bf16x8*)(alds + (mt * 16 + l15) * ASTR + quad * 16 + kc * 64);

#pragma unroll
  for (int half = 0; half < 2; ++half) {
    int j = wave * 32 + half * 16 + l15;
    f32x4 acc[4][4];                         // [q][mt]
#pragma unroll
    for (int q = 0; q < 4; ++q) {
      bf16x8 bfr[KC];
#pragma unroll
      for (int kc = 0; kc < KC; ++kc) {
        const float* p = Wih + (size_t)(q * 128 + j) * K + quad * 8 + kc * 32;
        bfr[kc] = pack8(*(const f32x4*)p, *(const f32x4*)(p + 4));
      }
#pragma unroll
      for (int mt = 0; mt < 4; ++mt) acc[q][mt] = (f32x4){0.f,0.f,0.f,0.f};
#pragma unroll
      for (int kc = 0; kc < KC; ++kc)
#pragma unroll
        for (int mt = 0; mt < 4; ++mt)
          acc[q][mt] = __builtin_amdgcn_mfma_f32_16x16x32_bf16(af[mt][kc], bfr[kc], acc[q][mt], 0, 0, 0);
    }
    float bs[4];
#pragma unroll
    for (int q = 0; q < 4; ++q) bs[q] = bih[q * 128 + j] + bhh[q * 128 + j];
#pragma unroll
    for (int mt = 0; mt < 4; ++mt)
#pragma unroll
      for (int r = 0; r < 4; ++r) {
        size_t row = M0 + mt * 16 + quad * 4 + r;
        bf16x4 o;
#pragma unroll
        for (int q = 0; q < 4; ++q) o[q] = (short)f2bf(acc[q][mt][r] + bs[q]);
        *(bf16x4*)(xg + row * 512 + j * 4) = o;
      }
  }
}

// ---------------- recurrence ----------------
// WG=512 (8 waves), NB=4. Thread (wave,quad,l15) owns (b=bg0+quad, j=wave*16+l15).
// h exchanged in COMPRESSED A-order (1 KB): h[b][k] at byte
//   (k>>5)*256 + (((k>>3)&3)*4 + b)*16 + (k&7)*2.
// A row m is defined as h[m>>2] (batch replicated 4x): readers load
//   kc*256 + (quad*4 + (l15>>2))*16  (4-lane broadcast, 256B contiguous,
//   conflict-free). C rows quad*4+r then all hold batch `quad`; reg0 is used.
template<int IS_LAST>
__global__ __launch_bounds__(512, 2) void lstm_rec(
    const unsigned short* __restrict__ xg,    // [B][T][128][4] bf16
    const float* __restrict__ Whh,            // [512][128]
    const float* __restrict__ h0, const float* __restrict__ c0,
    float* __restrict__ hN, float* __restrict__ cN,
    unsigned short* __restrict__ y_out,       // [B][T][128] bf16 (layers 0,1)
    float* __restrict__ outp,                 // [B][T] (layer 2)
    const float* __restrict__ Wout, const float* __restrict__ boutp)
{
  __shared__ __align__(16) char hA[2][1024];
  int tid = threadIdx.x, wave = tid >> 6, lane = tid & 63, quad = lane >> 4, l15 = lane & 15;
  int bg0 = blockIdx.x * NB;
  int b = bg0 + quad;
  int j = wave * 16 + l15;

  // Whh B-frags -> 64 VGPR: tile n = q*128 + j, k = quad*8 + kc*32 + e
  bf16x8 bw[4][4];
#pragma unroll
  for (int q = 0; q < 4; ++q)
#pragma unroll
    for (int kc = 0; kc < 4; ++kc) {
      const float* p = Whh + (size_t)(q * 128 + j) * HH + quad * 8 + kc * 32;
      bw[q][kc] = pack8(*(const f32x4*)p, *(const f32x4*)(p + 4));
    }

  // write offset for h[b=quad][k=j]
  int off_w = (wave >> 1) * 256 + (((((wave & 1) << 1) | (l15 >> 3)) * 4) + quad) * 16 + (l15 & 7) * 2;
  // read base (per-kc offset +256 each)
  int off_r = (quad * 4 + (l15 >> 2)) * 16;

  *(unsigned short*)(hA[0] + off_w) = f2bf(h0[(size_t)b * HH + j]);
  float cc = c0[(size_t)b * HH + j];

  // projection setup (layer 2): tid<128, 32 threads per batch
  f32x4 wv = {0.f,0.f,0.f,0.f};
  float ob = 0.f;
  int prd_off = 0, pbl = 0;
  if (IS_LAST && tid < 128) {
    pbl = tid >> 5;
    int j4 = (tid & 31) * 4;
    wv = *(const f32x4*)(Wout + j4);
    ob = boutp[0];
    prd_off = (j4 >> 5) * 256 + ((((j4 >> 3) & 3) * 4) + pbl) * 16 + (j4 & 7) * 2;
  }

  // xg register prefetch, depth PD
  const unsigned short* xp = xg + (size_t)b * (TT * 512) + j * 4;
  bf16x4 xq[PD];
#pragma unroll
  for (int u = 0; u < PD; ++u) xq[u] = *(const bf16x4*)(xp + u * 512);
  xp += PD * 512;

  unsigned short* yo = nullptr;
  if (!IS_LAST) yo = y_out + (size_t)b * TT * HH + j;

  bar_lds();

  const f32x4 z4 = {0.f, 0.f, 0.f, 0.f};
  float hv = 0.f;

  for (int t4 = 0; t4 < TT / PD; ++t4) {
#pragma unroll
    for (int u = 0; u < PD; ++u) {
      int t = t4 * PD + u;
      char* cur = hA[u & 1];          // holds h_{t-1}
      char* nxt = hA[(u & 1) ^ 1];

      // h A-frags: broadcast reads, 256B unique each
      bf16x8 a0 = *(const bf16x8*)(cur + off_r);
      bf16x8 a1 = *(const bf16x8*)(cur + 256 + off_r);
      bf16x8 a2 = *(const bf16x8*)(cur + 512 + off_r);
      bf16x8 a3 = *(const bf16x8*)(cur + 768 + off_r);

      // consume prefetched xg, reissue for t+PD
      float xv0 = bf2f((unsigned short)xq[u][0]);
      float xv1 = bf2f((unsigned short)xq[u][1]);
      float xv2 = bf2f((unsigned short)xq[u][2]);
      float xv3 = bf2f((unsigned short)xq[u][3]);
      if (t4 < TT / PD - 1) xq[u] = *(const bf16x4*)xp;
      xp += 512;

      // two independent 2-deep MFMA chains per gate
      f32x4 c01[4], c23[4];
#pragma unroll
      for (int q = 0; q < 4; ++q) c01[q] = __builtin_amdgcn_mfma_f32_16x16x32_bf16(a0, bw[q][0], z4, 0, 0, 0);
#pragma unroll
      for (int q = 0; q < 4; ++q) c23[q] = __builtin_amdgcn_mfma_f32_16x16x32_bf16(a2, bw[q][2], z4, 0, 0, 0);
#pragma unroll
      for (int q = 0; q < 4; ++q) c01[q] = __builtin_amdgcn_mfma_f32_16x16x32_bf16(a1, bw[q][1], c01[q], 0, 0, 0);
#pragma unroll
      for (int q = 0; q < 4; ++q) c23[q] = __builtin_amdgcn_mfma_f32_16x16x32_bf16(a3, bw[q][3], c23[q], 0, 0, 0);

      // overlapped projection of h_{t-1} (in cur) for layer 2
      if (IS_LAST && t > 0 && tid < 128) {
        bf16x4 hv4 = *(const bf16x4*)(cur + prd_off);
        float s = bf2f((unsigned short)hv4[0]) * wv[0] + bf2f((unsigned short)hv4[1]) * wv[1]
                + bf2f((unsigned short)hv4[2]) * wv[2] + bf2f((unsigned short)hv4[3]) * wv[3];
#pragma unroll
        for (int off = 16; off > 0; off >>= 1) s += __shfl_xor(s, off, 32);
        if ((tid & 31) == 0) outp[(size_t)(bg0 + pbl) * TT + (t - 1)] = fmaxf(s + ob, 0.f);
      }

      // gates + state (fp32), only C reg0 is live
      float gi = fsig(c01[0][0] + c23[0][0] + xv0);
      float gf = fsig(c01[1][0] + c23[1][0] + xv1);
      float gg = ftanh(c01[2][0] + c23[2][0] + xv2);
      float go = fsig(c01[3][0] + c23[3][0] + xv3);
      cc = gf * cc + gi * gg;
      hv = go * ftanh(cc);
      unsigned short hb = f2bf(hv);
      *(unsigned short*)(nxt + off_w) = hb;
      if (!IS_LAST) yo[(size_t)t * HH] = hb;
      bar_lds();
    }
  }

  hN[(size_t)b * HH + j] = hv;
  cN[(size_t)b * HH + j] = cc;

  if (IS_LAST && tid < 128) {   // h_1023 lives in hA[0]
    bf16x4 hv4 = *(const bf16x4*)(hA[0] + prd_off);
    float s = bf2f((unsigned short)hv4[0]) * wv[0] + bf2f((unsigned short)hv4[1]) * wv[1]
            + bf2f((unsigned short)hv4[2]) * wv[2] + bf2f((unsigned short)hv4[3]) * wv[3];
#pragma unroll
    for (int off = 16; off > 0; off >>= 1) s += __shfl_xor(s, off, 32);
    if ((tid & 31) == 0) outp[(size_t)(bg0 + pbl) * TT + (TT - 1)] = fmaxf(s + ob, 0.f);
  }
}

// ---------------- launch ----------------
extern "C" void kernel_launch(void* const* d_in, const int* in_sizes, int n_in,
                              void* d_out, int out_size, void* d_ws, size_t ws_size,
                              hipStream_t stream) {
  const float* x  = (const float*)d_in[0];
  const float* h0 = (const float*)d_in[1];
  const float* c0 = (const float*)d_in[2];
  const float* Wih[3] = {(const float*)d_in[3], (const float*)d_in[7],  (const float*)d_in[11]};
  const float* Whh[3] = {(const float*)d_in[4], (const float*)d_in[8],  (const float*)d_in[12]};
  const float* bih[3] = {(const float*)d_in[5], (const float*)d_in[9],  (const float*)d_in[13]};
  const float* bhh[3] = {(const float*)d_in[6], (const float*)d_in[10], (const float*)d_in[14]};
  const float* Wout = (const float*)d_in[15];
  const float* bout = (const float*)d_in[16];

  float* outp = (float*)d_out;                 // [B][T]
  float* hN = outp + BATCH * TT;               // [L][B][H]
  float* cN = hN + 3 * BATCH * HH;

  char* ws = (char*)d_ws;
  unsigned short* x_bf = (unsigned short*)ws;                      // 16 MB
  unsigned short* y_bf = (unsigned short*)(ws + (size_t)16777216); // 32 MB
  unsigned short* xg   = (unsigned short*)(ws + (size_t)50331648); // 128 MB

  cvt_bf16<<<8192, 256, 0, stream>>>(x, x_bf, BATCH * TT * DD);

  xg_gemm<64><<<2048, 256, 0, stream>>>(x_bf, Wih[0], bih[0], bhh[0], xg);
  lstm_rec<0><<<BATCH / NB, 512, 0, stream>>>(xg, Whh[0], h0, c0,
                                              hN, cN, y_bf, nullptr, Wout, bout);

  xg_gemm<128><<<2048, 256, 0, stream>>>(y_bf, Wih[1], bih[1], bhh[1], xg);
  lstm_rec<0><<<BATCH / NB, 512, 0, stream>>>(xg, Whh[1], h0 + BATCH * HH, c0 + BATCH * HH,
                                              hN + BATCH * HH, cN + BATCH * HH, y_bf, nullptr, Wout, bout);

  xg_gemm<128><<<2048, 256, 0, stream>>>(y_bf, Wih[2], bih[2], bhh[2], xg);
  lstm_rec<1><<<BATCH / NB, 512, 0, stream>>>(xg, Whh[2], h0 + 2 * BATCH * HH, c0 + 2 * BATCH * HH,
                                              hN + 2 * BATCH * HH, cN + 2 * BATCH * HH, nullptr, outp, Wout, bout);
}